// Round 14
// baseline (32.584 us; speedup 1.0000x reference)
//
#include <hip/hip_runtime.h>
#include <hip/hip_bf16.h>

// out[e] = concat(h[i0], h[i1]) @ W + b, h = logmap0(x)
// Rewritten: y[n][0:4] = h[n]·W[0:128,:] + b   (b folded here)
//            y[n][4:8] = h[n]·W[128:256,:]
//            out[e][c] = y[i0][c] + y[i1][4+c]
//
// R14 node: lane = node. W accessed with compile-time-uniform indices ->
// scalarized to s_load (SGPR operand in v_fmac, scalar-cache-resident).
// NO LDS, NO shuffles, no cross-lane anything. x row (512B) consumed in 4
// register chunks, software-pipelined (load chunk c+1 during FMAs of c).
// Block=64 (1 wave): 1563 blocks -> ~6/CU, fine-grained tail balance.

#define DIM 128

typedef float f32x4 __attribute__((ext_vector_type(4)));
typedef int   i32x2 __attribute__((ext_vector_type(2)));

__global__ __launch_bounds__(64) void node_proj_kernel(
    const float* __restrict__ x, const float* __restrict__ W,
    const float* __restrict__ b, float* __restrict__ y, int n_nodes)
{
    const int n = blockIdx.x * 64 + threadIdx.x;    // lane = node
    if (n >= n_nodes) return;

    const f32x4* xp = (const f32x4*)(x + (size_t)n * DIM);

    float acc[9];
#pragma unroll
    for (int i = 0; i < 9; ++i) acc[i] = 0.f;

    // 4 chunks of 32 dims; 2-deep pipeline, fully unrolled (static indices).
    f32x4 cur[8], nxt[8];
#pragma unroll
    for (int q = 0; q < 8; ++q) cur[q] = xp[q];

#pragma unroll
    for (int c = 0; c < 4; ++c) {
        if (c < 3) {
#pragma unroll
            for (int q = 0; q < 8; ++q) nxt[q] = xp[(c + 1) * 8 + q];
        }
#pragma unroll
        for (int q = 0; q < 8; ++q) {
#pragma unroll
            for (int k = 0; k < 4; ++k) {
                const int d = c * 32 + q * 4 + k;     // compile-time constant
                const float a = cur[q][k];
                const float* Wd = W + 4 * d;          // uniform -> s_load
                acc[0] = fmaf(a, a, acc[0]);
                acc[1] = fmaf(a, Wd[0], acc[1]);      // W[d][0:4]
                acc[2] = fmaf(a, Wd[1], acc[2]);
                acc[3] = fmaf(a, Wd[2], acc[3]);
                acc[4] = fmaf(a, Wd[3], acc[4]);
                acc[5] = fmaf(a, Wd[512], acc[5]);    // W[128+d][0:4]
                acc[6] = fmaf(a, Wd[513], acc[6]);
                acc[7] = fmaf(a, Wd[514], acc[7]);
                acc[8] = fmaf(a, Wd[515], acc[8]);
            }
        }
#pragma unroll
        for (int q = 0; q < 8; ++q) cur[q] = nxt[q];
    }

    // Per-lane epilogue (no divergence: all lanes do the same).
    float norm = fmaxf(sqrtf(acc[0]), 1e-15f);           // MIN_NORM
    const float aa  = fminf(norm, 1.0f - 1e-6f);         // ATANH_EPS clip
    const float art = 0.5f * log1pf(2.0f * aa / (1.0f - aa));  // artanh
    const float scale = art / norm;

    f32x4 o0, o1;
    o0[0] = fmaf(acc[1], scale, b[0]);    // b uniform -> s_load
    o0[1] = fmaf(acc[2], scale, b[1]);
    o0[2] = fmaf(acc[3], scale, b[2]);
    o0[3] = fmaf(acc[4], scale, b[3]);
    o1[0] = acc[5] * scale;
    o1[1] = acc[6] * scale;
    o1[2] = acc[7] * scale;
    o1[3] = acc[8] * scale;

    f32x4* yp = (f32x4*)(y + (size_t)n * 8);
    yp[0] = o0;
    yp[1] = o1;
}

// 1 edge per thread, exact grid: maximum outstanding gathers (R10 lesson:
// gathers are latency-bound -> TLP is the lever). idx/out nontemporal
// (streaming; keeps the 3.2 MB y table L2-resident); y gathers plain.
__global__ __launch_bounds__(256) void edge_kernel(
    const int* __restrict__ idx, const float* __restrict__ y,
    float* __restrict__ out, int n_edges)
{
    const int e = blockIdx.x * blockDim.x + threadIdx.x;
    if (e >= n_edges) return;
    const i32x2 ii = __builtin_nontemporal_load((const i32x2*)idx + e);
    const f32x4 a0 = *(const f32x4*)(y + (size_t)ii[0] * 8);
    const f32x4 c0 = *(const f32x4*)(y + (size_t)ii[1] * 8 + 4);
    const f32x4 o0 = a0 + c0;
    __builtin_nontemporal_store(o0, (f32x4*)out + e);
}

extern "C" void kernel_launch(void* const* d_in, const int* in_sizes, int n_in,
                              void* d_out, int out_size, void* d_ws, size_t ws_size,
                              hipStream_t stream) {
    const float* x   = (const float*)d_in[0];
    const int*   idx = (const int*)d_in[1];
    const float* W   = (const float*)d_in[2];
    const float* b   = (const float*)d_in[3];
    float* out = (float*)d_out;

    const int n_nodes = in_sizes[0] / DIM;
    const int n_edges = in_sizes[1] / 2;

    float* y = (float*)d_ws;  // n_nodes * 8 floats = 3.2 MB

    // Node: 1 node per lane, 64-thread (1-wave) blocks.
    const int blocks1 = (n_nodes + 63) / 64;
    node_proj_kernel<<<blocks1, 64, 0, stream>>>(x, W, b, y, n_nodes);

    // Edge: 1 edge/thread, exact grid (1M threads).
    const int blocks2 = (n_edges + 255) / 256;
    edge_kernel<<<blocks2, 256, 0, stream>>>(idx, y, out, n_edges);
}

// Round 15
// 31.464 us; speedup vs baseline: 1.0356x; 1.0356x over previous
//
#include <hip/hip_runtime.h>
#include <hip/hip_bf16.h>

// out[e] = concat(h[i0], h[i1]) @ W + b, h = logmap0(x)
// Rewritten: y[n][0:4] = h[n]·W[0:128,:] + b   (b folded here)
//            y[n][4:8] = h[n]·W[128:256,:]
//            out[e][c] = y[i0][c] + y[i1][4+c]
//
// R15 node: 8 lanes per node (16 dims each) -> 12.5K waves -> occupancy
// pinned at the 32-waves/CU cap (R12-R14 showed node is cold-HBM-latency
// bound; in-flight bytes x waves is the lever; prior variants had <=12
// waves/CU). W packed in LDS at float-offset f(d)=8d+4(d>>4): the 8
// distinct addresses per ds_read_b128 instruction start at banks
// {base+4*li}, li=0..7 -> 8 distinct bank-quads, conflict-free.

#define DIM 128

typedef float f32x4 __attribute__((ext_vector_type(4)));
typedef int   i32x2 __attribute__((ext_vector_type(2)));

__global__ __launch_bounds__(256) void node_proj_kernel(
    const float* __restrict__ x, const float* __restrict__ W,
    const float* __restrict__ b, float* __restrict__ y, int n_nodes)
{
    __shared__ float wp[1056];
    const int t = threadIdx.x;
    {
        // Pack [W[d][0:4] | W[d+128][0:4]] at f(d)=8d+4(d>>4).
        const f32x4 wv = ((const f32x4*)W)[t];        // W row t (t<256)
        const int r = t & 127, h = t >> 7;
        *(f32x4*)(wp + r * 8 + (r >> 4) * 4 + h * 4) = wv;
    }
    __syncthreads();

    const int lane = t & 63;
    const int li   = lane & 7;          // dim-slice owner (16 dims)
    const int g    = lane >> 3;         // node within wave (8 nodes/wave)
    const int n    = blockIdx.x * 32 + (t >> 6) * 8 + g;
    if (n >= n_nodes) return;

    const f32x4* xp = (const f32x4*)(x + (size_t)n * DIM + li * 16);
    const float* wl = wp + li * 132;    // f(16*li) = 132*li

    // 16 dims per lane: 4 dense dwordx4 loads.
    f32x4 xa[4];
#pragma unroll
    for (int q = 0; q < 4; ++q) xa[q] = xp[q];

    float acc[9];
#pragma unroll
    for (int i = 0; i < 9; ++i) acc[i] = 0.f;

#pragma unroll
    for (int q = 0; q < 4; ++q) {
#pragma unroll
        for (int k = 0; k < 4; ++k) {
            const int idx = q * 4 + k;                 // 0..15
            const f32x4 wa = *(const f32x4*)(wl + idx * 8);      // W[d][0:4]
            const f32x4 wb = *(const f32x4*)(wl + idx * 8 + 4);  // W[d+128][0:4]
            const float a = xa[q][k];
            acc[0] = fmaf(a, a, acc[0]);
            acc[1] = fmaf(a, wa[0], acc[1]);
            acc[2] = fmaf(a, wa[1], acc[2]);
            acc[3] = fmaf(a, wa[2], acc[3]);
            acc[4] = fmaf(a, wa[3], acc[4]);
            acc[5] = fmaf(a, wb[0], acc[5]);
            acc[6] = fmaf(a, wb[1], acc[6]);
            acc[7] = fmaf(a, wb[2], acc[7]);
            acc[8] = fmaf(a, wb[3], acc[8]);
        }
    }

    // 3-round butterfly across the 8-lane group (xor 1,2,4).
#pragma unroll
    for (int i = 0; i < 9; ++i) {
        acc[i] += __shfl_xor(acc[i], 1, 64);
        acc[i] += __shfl_xor(acc[i], 2, 64);
        acc[i] += __shfl_xor(acc[i], 4, 64);
    }

    // li=0 writes y[n][0:4] (+bias), li=1 writes y[n][4:8].
    if (li < 2) {
        const bool second = li;

        float norm = fmaxf(sqrtf(acc[0]), 1e-15f);           // MIN_NORM
        const float aa  = fminf(norm, 1.0f - 1e-6f);         // ATANH_EPS clip
        const float art = 0.5f * log1pf(2.0f * aa / (1.0f - aa));  // artanh
        const float scale = art / norm;

        const float w0 = second ? acc[5] : acc[1];
        const float w1 = second ? acc[6] : acc[2];
        const float w2 = second ? acc[7] : acc[3];
        const float w3 = second ? acc[8] : acc[4];

        const f32x4 bv4 = *(const f32x4*)b;
        f32x4 o;
        o[0] = fmaf(w0, scale, second ? 0.f : bv4[0]);
        o[1] = fmaf(w1, scale, second ? 0.f : bv4[1]);
        o[2] = fmaf(w2, scale, second ? 0.f : bv4[2]);
        o[3] = fmaf(w3, scale, second ? 0.f : bv4[3]);

        *(f32x4*)(y + (size_t)n * 8 + li * 4) = o;
    }
}

// 1 edge per thread, exact grid: maximum outstanding gathers (R10 lesson:
// gathers are latency-bound -> TLP is the lever). idx/out nontemporal
// (streaming; keeps the 3.2 MB y table L2-resident); y gathers plain.
__global__ __launch_bounds__(256) void edge_kernel(
    const int* __restrict__ idx, const float* __restrict__ y,
    float* __restrict__ out, int n_edges)
{
    const int e = blockIdx.x * blockDim.x + threadIdx.x;
    if (e >= n_edges) return;
    const i32x2 ii = __builtin_nontemporal_load((const i32x2*)idx + e);
    const f32x4 a0 = *(const f32x4*)(y + (size_t)ii[0] * 8);
    const f32x4 c0 = *(const f32x4*)(y + (size_t)ii[1] * 8 + 4);
    const f32x4 o0 = a0 + c0;
    __builtin_nontemporal_store(o0, (f32x4*)out + e);
}

extern "C" void kernel_launch(void* const* d_in, const int* in_sizes, int n_in,
                              void* d_out, int out_size, void* d_ws, size_t ws_size,
                              hipStream_t stream) {
    const float* x   = (const float*)d_in[0];
    const int*   idx = (const int*)d_in[1];
    const float* W   = (const float*)d_in[2];
    const float* b   = (const float*)d_in[3];
    float* out = (float*)d_out;

    const int n_nodes = in_sizes[0] / DIM;
    const int n_edges = in_sizes[1] / 2;

    float* y = (float*)d_ws;  // n_nodes * 8 floats = 3.2 MB

    // Node: 8 lanes/node -> 8 nodes/wave -> 32 nodes/block (256 thr).
    // 3125 blocks -> ~12 blocks/CU -> occupancy pinned at 32 waves/CU.
    const int blocks1 = (n_nodes + 31) / 32;
    node_proj_kernel<<<blocks1, 256, 0, stream>>>(x, W, b, y, n_nodes);

    // Edge: 1 edge/thread, exact grid (1M threads).
    const int blocks2 = (n_edges + 255) / 256;
    edge_kernel<<<blocks2, 256, 0, stream>>>(idx, y, out, n_edges);
}